// Round 6
// baseline (408.390 us; speedup 1.0000x reference)
//
#include <hip/hip_runtime.h>

#define D 128
#define BN_EPS 1e-5f
#define GROWS 32
#define KT 32

// ---- K1: in-degree histogram (int atomics) ----
__global__ void k_hist(const int* __restrict__ dst, int* __restrict__ deg, int nE) {
    int e = blockIdx.x * 256 + threadIdx.x;
    if (e < nE) atomicAdd(&deg[dst[e]], 1);
}

// ---- K2: claim CSR slot ranges (unordered) + norm ----
__global__ __launch_bounds__(256) void k_claim(const int* __restrict__ deg,
                                               int* __restrict__ offs,
                                               int* __restrict__ cursor,
                                               float* __restrict__ norm,
                                               int* __restrict__ counter, int nN) {
    int i = blockIdx.x * 256 + threadIdx.x;
    int lane = threadIdx.x & 63;
    int d = (i < nN) ? deg[i] : 0;
    int x = d;
    #pragma unroll
    for (int off = 1; off < 64; off <<= 1) {
        int v = __shfl_up(x, off, 64);
        if (lane >= off) x += v;
    }
    int total = __shfl(x, 63, 64);
    int base = 0;
    if (lane == 63 && total > 0) base = atomicAdd(counter, total);
    base = __shfl(base, 63, 64);
    if (i < nN) {
        int o = base + x - d;
        offs[i] = o;
        cursor[i] = o;
        norm[i] = rsqrtf(fmaxf((float)d, 1.0f));
    }
}

// ---- K3: bucket edges by dst: srcs[slot] = src ----
__global__ void k_bucket(const int* __restrict__ src, const int* __restrict__ dst,
                         int* __restrict__ cursor, int* __restrict__ srcs, int nE) {
    int e = blockIdx.x * 256 + threadIdx.x;
    if (e < nE) {
        int d = dst[e];
        int slot = atomicAdd(&cursor[d], 1);
        srcs[slot] = src[e];
    }
}

// ---- K4: gather-aggregate: one node per 64-lane wave, float2 per lane ----
__global__ __launch_bounds__(256) void k_gather(const int* __restrict__ offs,
                                                const int* __restrict__ deg,
                                                const int* __restrict__ srcs,
                                                const float* __restrict__ feat,
                                                const float* __restrict__ norm,
                                                float* __restrict__ agg, int nN) {
    int node = (blockIdx.x * 256 + threadIdx.x) >> 6;
    if (node >= nN) return;
    int lane = threadIdx.x & 63;
    const float* fbase = feat + 2 * lane;

    int i = offs[node];
    int end = i + deg[node];
    float ax = 0.0f, ay = 0.0f;

    for (; i + 3 < end; i += 4) {
        int s0 = srcs[i], s1 = srcs[i + 1], s2 = srcs[i + 2], s3 = srcs[i + 3];
        float n0 = norm[s0], n1 = norm[s1], n2 = norm[s2], n3 = norm[s3];
        float2 f0 = *(const float2*)(fbase + (size_t)s0 * D);
        float2 f1 = *(const float2*)(fbase + (size_t)s1 * D);
        float2 f2 = *(const float2*)(fbase + (size_t)s2 * D);
        float2 f3 = *(const float2*)(fbase + (size_t)s3 * D);
        ax += f0.x * n0 + f1.x * n1 + f2.x * n2 + f3.x * n3;
        ay += f0.y * n0 + f1.y * n1 + f2.y * n2 + f3.y * n3;
    }
    for (; i < end; ++i) {
        int s = srcs[i];
        float n = norm[s];
        float2 f = *(const float2*)(fbase + (size_t)s * D);
        ax += f.x * n;
        ay += f.y * n;
    }
    float2 o = {ax, ay};
    *(float2*)(agg + (size_t)node * D + 2 * lane) = o;
}

// ---- K5: h = (agg @ W^T + b) * norm, in-place; BN partial sums ----
// 32 rows/block, 256 threads, 4x4 tile/thread, KT=32, W register-prefetch.
// LDS = 16896 + 16384 + 1024 = 34304 B -> 4 blocks/CU (16 waves).
__global__ __launch_bounds__(256, 4) void k_gemm(
        float* agg,
        const float* __restrict__ W,
        const float* __restrict__ b,
        const float* __restrict__ norm,
        float* __restrict__ colsum, float* __restrict__ colsq,
        int nN) {
    __shared__ float Wt[KT][132];        // Wt[kk][j] = W[j][kt+kk]
    __shared__ float arow[GROWS][128];
    __shared__ float red[256];

    const int tid = threadIdx.x;
    const int row0 = blockIdx.x * GROWS;

    red[tid] = 0.0f;

    // Stage A rows into LDS (float4, coalesced; 2-way write aliasing = free)
    for (int idx4 = tid; idx4 < (GROWS * 128 / 4); idx4 += 256) {
        int r = idx4 >> 5;
        int k0 = (idx4 & 31) << 2;
        int gr = row0 + r;
        float4 v = {0.0f, 0.0f, 0.0f, 0.0f};
        if (gr < nN) v = *(const float4*)(agg + (size_t)gr * 128 + k0);
        *(float4*)(&arow[r][k0]) = v;
    }

    // W prefetch: tile = 128x32 floats = 1024 float4 / 256 threads = 4 each.
    // item idx -> j = idx&127 (row of W), q = idx>>7 (k-quad).
    float4 wreg[4];
    #pragma unroll
    for (int it = 0; it < 4; ++it) {
        int idx = tid + 256 * it;
        int j = idx & 127, q = idx >> 7;
        wreg[it] = *(const float4*)(W + (size_t)j * 128 + 4 * q);
    }

    const int jg = tid & 31, rg = tid >> 5;
    const int j0 = jg << 2, r0 = rg << 2;

    float sum[4][4];
    #pragma unroll
    for (int r = 0; r < 4; r++)
        #pragma unroll
        for (int c = 0; c < 4; c++) sum[r][c] = 0.0f;

    for (int kt = 0; kt < 128; kt += KT) {
        __syncthreads();   // Wt free to overwrite (first iter: also covers arow staging)
        // Write prefetched W tile into Wt (bank = (16q+4c+j)%32, j spans 64 -> 2-way, free)
        #pragma unroll
        for (int it = 0; it < 4; ++it) {
            int idx = tid + 256 * it;
            int j = idx & 127, q = idx >> 7;
            float4 w = wreg[it];
            Wt[4 * q + 0][j] = w.x;
            Wt[4 * q + 1][j] = w.y;
            Wt[4 * q + 2][j] = w.z;
            Wt[4 * q + 3][j] = w.w;
        }
        __syncthreads();
        // Prefetch next tile while computing this one
        if (kt + KT < 128) {
            #pragma unroll
            for (int it = 0; it < 4; ++it) {
                int idx = tid + 256 * it;
                int j = idx & 127, q = idx >> 7;
                wreg[it] = *(const float4*)(W + (size_t)j * 128 + (kt + KT) + 4 * q);
            }
        }

        for (int kk = 0; kk < KT; kk += 4) {
            float4 w0 = *(const float4*)(&Wt[kk + 0][j0]);   // natural 4-phase b128, no extra conflict
            float4 w1 = *(const float4*)(&Wt[kk + 1][j0]);
            float4 w2 = *(const float4*)(&Wt[kk + 2][j0]);
            float4 w3 = *(const float4*)(&Wt[kk + 3][j0]);
            #pragma unroll
            for (int r = 0; r < 4; r++) {
                float4 a = *(const float4*)(&arow[r0 + r][kt + kk]);
                sum[r][0] += a.x * w0.x + a.y * w1.x + a.z * w2.x + a.w * w3.x;
                sum[r][1] += a.x * w0.y + a.y * w1.y + a.z * w2.y + a.w * w3.y;
                sum[r][2] += a.x * w0.z + a.y * w1.z + a.z * w2.z + a.w * w3.z;
                sum[r][3] += a.x * w0.w + a.y * w1.w + a.z * w2.w + a.w * w3.w;
            }
        }
    }

    const float bj0 = b[j0], bj1 = b[j0 + 1], bj2 = b[j0 + 2], bj3 = b[j0 + 3];
    float s1[4] = {0, 0, 0, 0}, s2[4] = {0, 0, 0, 0};
    #pragma unroll
    for (int r = 0; r < 4; r++) {
        int gr = row0 + r0 + r;
        if (gr < nN) {
            float nm = norm[gr];
            float4 hv;
            hv.x = (sum[r][0] + bj0) * nm;
            hv.y = (sum[r][1] + bj1) * nm;
            hv.z = (sum[r][2] + bj2) * nm;
            hv.w = (sum[r][3] + bj3) * nm;
            *(float4*)(agg + (size_t)gr * 128 + j0) = hv;
            s1[0] += hv.x; s1[1] += hv.y; s1[2] += hv.z; s1[3] += hv.w;
            s2[0] += hv.x * hv.x; s2[1] += hv.y * hv.y; s2[2] += hv.z * hv.z; s2[3] += hv.w * hv.w;
        }
    }

    #pragma unroll
    for (int c = 0; c < 4; c++) {
        atomicAdd(&red[j0 + c], s1[c]);
        atomicAdd(&red[128 + j0 + c], s2[c]);
    }
    __syncthreads();
    if (tid < 128) {
        atomicAdd(&colsum[tid], red[tid]);
        atomicAdd(&colsq[tid], red[128 + tid]);
    }
}

// ---- K6: BN parameter fold ----
__global__ void k_bnparam(const float* __restrict__ colsum, const float* __restrict__ colsq,
                          const float* __restrict__ gamma, const float* __restrict__ beta,
                          float* __restrict__ scale, float* __restrict__ shift, int nN) {
    int j = threadIdx.x;
    float inv_n = 1.0f / (float)nN;
    float mean = colsum[j] * inv_n;
    float var = colsq[j] * inv_n - mean * mean;
    float sc = gamma[j] * rsqrtf(var + BN_EPS);
    scale[j] = sc;
    shift[j] = beta[j] - mean * sc;
}

// ---- K7: out = feat + relu(h*scale + shift), in-place over h (= d_out) ----
__global__ void k_out(float* __restrict__ h, const float* __restrict__ feat,
                      const float* __restrict__ scale, const float* __restrict__ shift,
                      int total4) {
    int t = blockIdx.x * 256 + threadIdx.x;
    if (t >= total4) return;
    int base = t * 4;
    int j = base & 127;
    float4 hv = *(const float4*)(h + base);
    float4 fv = *(const float4*)(feat + base);
    float4 o;
    o.x = fv.x + fmaxf(hv.x * scale[j + 0] + shift[j + 0], 0.0f);
    o.y = fv.y + fmaxf(hv.y * scale[j + 1] + shift[j + 1], 0.0f);
    o.z = fv.z + fmaxf(hv.z * scale[j + 2] + shift[j + 2], 0.0f);
    o.w = fv.w + fmaxf(hv.w * scale[j + 3] + shift[j + 3], 0.0f);
    *(float4*)(h + base) = o;
}

extern "C" void kernel_launch(void* const* d_in, const int* in_sizes, int n_in,
                              void* d_out, int out_size, void* d_ws, size_t ws_size,
                              hipStream_t stream) {
    const float* feat  = (const float*)d_in[0];
    const float* W     = (const float*)d_in[1];
    const float* b     = (const float*)d_in[2];
    const float* gamma = (const float*)d_in[3];
    const float* beta  = (const float*)d_in[4];
    const int* esrc = (const int*)d_in[5];
    const int* edst = (const int*)d_in[6];

    const int nN = in_sizes[0] / D;
    const int nE = in_sizes[5];

    float* agg = (float*)d_out;

    int*   deg     = (int*)d_ws;          // nN
    int*   offs    = deg + nN;            // nN
    int*   cursor  = offs + nN;           // nN
    int*   srcs    = cursor + nN;         // nE
    float* norm    = (float*)(srcs + nE); // nN
    float* colsum  = norm + nN;           // 128
    float* colsq   = colsum + 128;        // 128
    float* scale   = colsq + 128;         // 128
    float* shift   = scale + 128;         // 128
    int*   counter = (int*)(shift + 128); // 1

    hipMemsetAsync(deg, 0, (size_t)nN * sizeof(int), stream);
    hipMemsetAsync(colsum, 0, (4 * 128 + 1) * sizeof(float), stream);

    k_hist<<<(nE + 255) / 256, 256, 0, stream>>>(edst, deg, nE);
    k_claim<<<(nN + 255) / 256, 256, 0, stream>>>(deg, offs, cursor, norm, counter, nN);
    k_bucket<<<(nE + 255) / 256, 256, 0, stream>>>(esrc, edst, cursor, srcs, nE);

    int gblocks = (nN * 64 + 255) / 256;
    k_gather<<<gblocks, 256, 0, stream>>>(offs, deg, srcs, feat, norm, agg, nN);

    k_gemm<<<(nN + GROWS - 1) / GROWS, 256, 0, stream>>>(agg, W, b, norm, colsum, colsq, nN);
    k_bnparam<<<1, 128, 0, stream>>>(colsum, colsq, gamma, beta, scale, shift, nN);

    int total4 = nN * D / 4;
    k_out<<<(total4 + 255) / 256, 256, 0, stream>>>(agg, feat, scale, shift, total4);
}

// Round 7
// 326.149 us; speedup vs baseline: 1.2522x; 1.2522x over previous
//
#include <hip/hip_runtime.h>

#define D 128
#define BN_EPS 1e-5f
#define GROWS 32
#define KT 32

// ---- K1: in-degree histogram (int atomics) ----
__global__ void k_hist(const int* __restrict__ dst, int* __restrict__ deg, int nE) {
    int e = blockIdx.x * 256 + threadIdx.x;
    if (e < nE) atomicAdd(&deg[dst[e]], 1);
}

// ---- K2: claim CSR slot ranges (unordered) + norm ----
__global__ __launch_bounds__(256) void k_claim(const int* __restrict__ deg,
                                               int* __restrict__ offs,
                                               int* __restrict__ cursor,
                                               float* __restrict__ norm,
                                               int* __restrict__ counter, int nN) {
    int i = blockIdx.x * 256 + threadIdx.x;
    int lane = threadIdx.x & 63;
    int d = (i < nN) ? deg[i] : 0;
    int x = d;
    #pragma unroll
    for (int off = 1; off < 64; off <<= 1) {
        int v = __shfl_up(x, off, 64);
        if (lane >= off) x += v;
    }
    int total = __shfl(x, 63, 64);
    int base = 0;
    if (lane == 63 && total > 0) base = atomicAdd(counter, total);
    base = __shfl(base, 63, 64);
    if (i < nN) {
        int o = base + x - d;
        offs[i] = o;
        cursor[i] = o;
        norm[i] = rsqrtf(fmaxf((float)d, 1.0f));
    }
}

// ---- K3: bucket edges by dst: srcs[slot] = src ----
__global__ void k_bucket(const int* __restrict__ src, const int* __restrict__ dst,
                         int* __restrict__ cursor, int* __restrict__ srcs, int nE) {
    int e = blockIdx.x * 256 + threadIdx.x;
    if (e < nE) {
        int d = dst[e];
        int slot = atomicAdd(&cursor[d], 1);
        srcs[slot] = src[e];
    }
}

// ---- K4: gather-aggregate: one node per 64-lane wave, float2 per lane ----
__global__ __launch_bounds__(256) void k_gather(const int* __restrict__ offs,
                                                const int* __restrict__ deg,
                                                const int* __restrict__ srcs,
                                                const float* __restrict__ feat,
                                                const float* __restrict__ norm,
                                                float* __restrict__ agg, int nN) {
    int node = (blockIdx.x * 256 + threadIdx.x) >> 6;
    if (node >= nN) return;
    int lane = threadIdx.x & 63;
    const float* fbase = feat + 2 * lane;

    int i = offs[node];
    int end = i + deg[node];
    float ax = 0.0f, ay = 0.0f;

    for (; i + 3 < end; i += 4) {
        int s0 = srcs[i], s1 = srcs[i + 1], s2 = srcs[i + 2], s3 = srcs[i + 3];
        float n0 = norm[s0], n1 = norm[s1], n2 = norm[s2], n3 = norm[s3];
        float2 f0 = *(const float2*)(fbase + (size_t)s0 * D);
        float2 f1 = *(const float2*)(fbase + (size_t)s1 * D);
        float2 f2 = *(const float2*)(fbase + (size_t)s2 * D);
        float2 f3 = *(const float2*)(fbase + (size_t)s3 * D);
        ax += f0.x * n0 + f1.x * n1 + f2.x * n2 + f3.x * n3;
        ay += f0.y * n0 + f1.y * n1 + f2.y * n2 + f3.y * n3;
    }
    for (; i < end; ++i) {
        int s = srcs[i];
        float n = norm[s];
        float2 f = *(const float2*)(fbase + (size_t)s * D);
        ax += f.x * n;
        ay += f.y * n;
    }
    float2 o = {ax, ay};
    *(float2*)(agg + (size_t)node * D + 2 * lane) = o;
}

// ---- K5: h = (agg @ W^T + b) * norm, in-place; BN partial sums ----
// 32 rows/block, 256 threads, 4x4 tile/thread, KT=32, W register-prefetch.
// LDS = 16896 + 16384 + 1024 = 34304 B -> 4 blocks/CU by LDS.
// NO min-waves launch_bounds: forcing 4 waves/EU capped VGPR at 64 and
// spilled ~500 MB of scratch traffic (R6: FETCH 181 MB, WRITE 371 MB).
__global__ __launch_bounds__(256) void k_gemm(
        float* agg,
        const float* __restrict__ W,
        const float* __restrict__ b,
        const float* __restrict__ norm,
        float* __restrict__ colsum, float* __restrict__ colsq,
        int nN) {
    __shared__ float Wt[KT][132];        // Wt[kk][j] = W[j][kt+kk]
    __shared__ float arow[GROWS][128];
    __shared__ float red[256];

    const int tid = threadIdx.x;
    const int row0 = blockIdx.x * GROWS;

    red[tid] = 0.0f;

    // Stage A rows into LDS (float4, coalesced; 2-way write aliasing = free)
    for (int idx4 = tid; idx4 < (GROWS * 128 / 4); idx4 += 256) {
        int r = idx4 >> 5;
        int k0 = (idx4 & 31) << 2;
        int gr = row0 + r;
        float4 v = {0.0f, 0.0f, 0.0f, 0.0f};
        if (gr < nN) v = *(const float4*)(agg + (size_t)gr * 128 + k0);
        *(float4*)(&arow[r][k0]) = v;
    }

    // W prefetch: tile = 128x32 floats = 1024 float4 / 256 threads = 4 each.
    // item idx -> j = idx&127 (row of W), q = idx>>7 (k-quad).
    float4 wreg[4];
    #pragma unroll
    for (int it = 0; it < 4; ++it) {
        int idx = tid + 256 * it;
        int j = idx & 127, q = idx >> 7;
        wreg[it] = *(const float4*)(W + (size_t)j * 128 + 4 * q);
    }

    const int jg = tid & 31, rg = tid >> 5;
    const int j0 = jg << 2, r0 = rg << 2;

    float sum[4][4];
    #pragma unroll
    for (int r = 0; r < 4; r++)
        #pragma unroll
        for (int c = 0; c < 4; c++) sum[r][c] = 0.0f;

    for (int kt = 0; kt < 128; kt += KT) {
        __syncthreads();   // Wt free to overwrite (first iter: also covers arow staging)
        // Write prefetched W tile into Wt (bank = (16q+4c+j)%32, j spans 64 -> 2-way, free)
        #pragma unroll
        for (int it = 0; it < 4; ++it) {
            int idx = tid + 256 * it;
            int j = idx & 127, q = idx >> 7;
            float4 w = wreg[it];
            Wt[4 * q + 0][j] = w.x;
            Wt[4 * q + 1][j] = w.y;
            Wt[4 * q + 2][j] = w.z;
            Wt[4 * q + 3][j] = w.w;
        }
        __syncthreads();
        // Prefetch next tile while computing this one
        if (kt + KT < 128) {
            #pragma unroll
            for (int it = 0; it < 4; ++it) {
                int idx = tid + 256 * it;
                int j = idx & 127, q = idx >> 7;
                wreg[it] = *(const float4*)(W + (size_t)j * 128 + (kt + KT) + 4 * q);
            }
        }

        for (int kk = 0; kk < KT; kk += 4) {
            float4 w0 = *(const float4*)(&Wt[kk + 0][j0]);   // natural 4-phase b128, no extra conflict
            float4 w1 = *(const float4*)(&Wt[kk + 1][j0]);
            float4 w2 = *(const float4*)(&Wt[kk + 2][j0]);
            float4 w3 = *(const float4*)(&Wt[kk + 3][j0]);
            #pragma unroll
            for (int r = 0; r < 4; r++) {
                float4 a = *(const float4*)(&arow[r0 + r][kt + kk]);
                sum[r][0] += a.x * w0.x + a.y * w1.x + a.z * w2.x + a.w * w3.x;
                sum[r][1] += a.x * w0.y + a.y * w1.y + a.z * w2.y + a.w * w3.y;
                sum[r][2] += a.x * w0.z + a.y * w1.z + a.z * w2.z + a.w * w3.z;
                sum[r][3] += a.x * w0.w + a.y * w1.w + a.z * w2.w + a.w * w3.w;
            }
        }
    }

    const float bj0 = b[j0], bj1 = b[j0 + 1], bj2 = b[j0 + 2], bj3 = b[j0 + 3];
    float s1[4] = {0, 0, 0, 0}, s2[4] = {0, 0, 0, 0};
    #pragma unroll
    for (int r = 0; r < 4; r++) {
        int gr = row0 + r0 + r;
        if (gr < nN) {
            float nm = norm[gr];
            float4 hv;
            hv.x = (sum[r][0] + bj0) * nm;
            hv.y = (sum[r][1] + bj1) * nm;
            hv.z = (sum[r][2] + bj2) * nm;
            hv.w = (sum[r][3] + bj3) * nm;
            *(float4*)(agg + (size_t)gr * 128 + j0) = hv;
            s1[0] += hv.x; s1[1] += hv.y; s1[2] += hv.z; s1[3] += hv.w;
            s2[0] += hv.x * hv.x; s2[1] += hv.y * hv.y; s2[2] += hv.z * hv.z; s2[3] += hv.w * hv.w;
        }
    }

    #pragma unroll
    for (int c = 0; c < 4; c++) {
        atomicAdd(&red[j0 + c], s1[c]);
        atomicAdd(&red[128 + j0 + c], s2[c]);
    }
    __syncthreads();
    if (tid < 128) {
        atomicAdd(&colsum[tid], red[tid]);
        atomicAdd(&colsq[tid], red[128 + tid]);
    }
}

// ---- K6: BN parameter fold ----
__global__ void k_bnparam(const float* __restrict__ colsum, const float* __restrict__ colsq,
                          const float* __restrict__ gamma, const float* __restrict__ beta,
                          float* __restrict__ scale, float* __restrict__ shift, int nN) {
    int j = threadIdx.x;
    float inv_n = 1.0f / (float)nN;
    float mean = colsum[j] * inv_n;
    float var = colsq[j] * inv_n - mean * mean;
    float sc = gamma[j] * rsqrtf(var + BN_EPS);
    scale[j] = sc;
    shift[j] = beta[j] - mean * sc;
}

// ---- K7: out = feat + relu(h*scale + shift), in-place over h (= d_out) ----
__global__ void k_out(float* __restrict__ h, const float* __restrict__ feat,
                      const float* __restrict__ scale, const float* __restrict__ shift,
                      int total4) {
    int t = blockIdx.x * 256 + threadIdx.x;
    if (t >= total4) return;
    int base = t * 4;
    int j = base & 127;
    float4 hv = *(const float4*)(h + base);
    float4 fv = *(const float4*)(feat + base);
    float4 o;
    o.x = fv.x + fmaxf(hv.x * scale[j + 0] + shift[j + 0], 0.0f);
    o.y = fv.y + fmaxf(hv.y * scale[j + 1] + shift[j + 1], 0.0f);
    o.z = fv.z + fmaxf(hv.z * scale[j + 2] + shift[j + 2], 0.0f);
    o.w = fv.w + fmaxf(hv.w * scale[j + 3] + shift[j + 3], 0.0f);
    *(float4*)(h + base) = o;
}

extern "C" void kernel_launch(void* const* d_in, const int* in_sizes, int n_in,
                              void* d_out, int out_size, void* d_ws, size_t ws_size,
                              hipStream_t stream) {
    const float* feat  = (const float*)d_in[0];
    const float* W     = (const float*)d_in[1];
    const float* b     = (const float*)d_in[2];
    const float* gamma = (const float*)d_in[3];
    const float* beta  = (const float*)d_in[4];
    const int* esrc = (const int*)d_in[5];
    const int* edst = (const int*)d_in[6];

    const int nN = in_sizes[0] / D;
    const int nE = in_sizes[5];

    float* agg = (float*)d_out;

    int*   deg     = (int*)d_ws;          // nN
    int*   offs    = deg + nN;            // nN
    int*   cursor  = offs + nN;           // nN
    int*   srcs    = cursor + nN;         // nE
    float* norm    = (float*)(srcs + nE); // nN
    float* colsum  = norm + nN;           // 128
    float* colsq   = colsum + 128;        // 128
    float* scale   = colsq + 128;         // 128
    float* shift   = scale + 128;         // 128
    int*   counter = (int*)(shift + 128); // 1

    hipMemsetAsync(deg, 0, (size_t)nN * sizeof(int), stream);
    hipMemsetAsync(colsum, 0, (4 * 128 + 1) * sizeof(float), stream);

    k_hist<<<(nE + 255) / 256, 256, 0, stream>>>(edst, deg, nE);
    k_claim<<<(nN + 255) / 256, 256, 0, stream>>>(deg, offs, cursor, norm, counter, nN);
    k_bucket<<<(nE + 255) / 256, 256, 0, stream>>>(esrc, edst, cursor, srcs, nE);

    int gblocks = (nN * 64 + 255) / 256;
    k_gather<<<gblocks, 256, 0, stream>>>(offs, deg, srcs, feat, norm, agg, nN);

    k_gemm<<<(nN + GROWS - 1) / GROWS, 256, 0, stream>>>(agg, W, b, norm, colsum, colsq, nN);
    k_bnparam<<<1, 128, 0, stream>>>(colsum, colsq, gamma, beta, scale, shift, nN);

    int total4 = nN * D / 4;
    k_out<<<(total4 + 255) / 256, 256, 0, stream>>>(agg, feat, scale, shift, total4);
}

// Round 8
// 275.611 us; speedup vs baseline: 1.4818x; 1.1834x over previous
//
#include <hip/hip_runtime.h>

#define D 128
#define BN_EPS 1e-5f

typedef __attribute__((ext_vector_type(8))) short short8;
typedef __attribute__((ext_vector_type(4))) float f32x4;

__device__ __forceinline__ unsigned short f2bf(float f) {
    unsigned int x = __float_as_uint(f);
    return (unsigned short)((x + 0x7fffu + ((x >> 16) & 1u)) >> 16);
}

// ---- cast fp32 -> bf16, float4 granularity ----
__global__ void k_cast(const float4* __restrict__ in, ushort4* __restrict__ out, int n4) {
    int i = blockIdx.x * 256 + threadIdx.x;
    if (i < n4) {
        float4 v = in[i];
        ushort4 o;
        o.x = f2bf(v.x); o.y = f2bf(v.y); o.z = f2bf(v.z); o.w = f2bf(v.w);
        out[i] = o;
    }
}

// ---- in-degree histogram ----
__global__ void k_hist(const int* __restrict__ dst, int* __restrict__ deg, int nE) {
    int e = blockIdx.x * 256 + threadIdx.x;
    if (e < nE) atomicAdd(&deg[dst[e]], 1);
}

// ---- claim CSR slot ranges (unordered) + norm ----
__global__ __launch_bounds__(256) void k_claim(const int* __restrict__ deg,
                                               int* __restrict__ offs,
                                               int* __restrict__ cursor,
                                               float* __restrict__ norm,
                                               int* __restrict__ counter, int nN) {
    int i = blockIdx.x * 256 + threadIdx.x;
    int lane = threadIdx.x & 63;
    int d = (i < nN) ? deg[i] : 0;
    int x = d;
    #pragma unroll
    for (int off = 1; off < 64; off <<= 1) {
        int v = __shfl_up(x, off, 64);
        if (lane >= off) x += v;
    }
    int total = __shfl(x, 63, 64);
    int base = 0;
    if (lane == 63 && total > 0) base = atomicAdd(counter, total);
    base = __shfl(base, 63, 64);
    if (i < nN) {
        int o = base + x - d;
        offs[i] = o;
        cursor[i] = o;
        norm[i] = rsqrtf(fmaxf((float)d, 1.0f));
    }
}

// ---- bucket edges by dst ----
__global__ void k_bucket(const int* __restrict__ src, const int* __restrict__ dst,
                         int* __restrict__ cursor, int* __restrict__ srcs, int nE) {
    int e = blockIdx.x * 256 + threadIdx.x;
    if (e < nE) {
        int d = dst[e];
        int slot = atomicAdd(&cursor[d], 1);
        srcs[slot] = src[e];
    }
}

// ---- gather-aggregate -> bf16 agg. One node per wave, 2 dims/lane.
// FB=true: feat already bf16 (ushort rows); FB=false: fp32 feat.
template <bool FB>
__global__ __launch_bounds__(256) void k_gather(const int* __restrict__ offs,
                                                const int* __restrict__ deg,
                                                const int* __restrict__ srcs,
                                                const void* __restrict__ featp,
                                                const float* __restrict__ norm,
                                                unsigned short* __restrict__ aggbf, int nN) {
    int node = (blockIdx.x * 256 + threadIdx.x) >> 6;
    if (node >= nN) return;
    int lane = threadIdx.x & 63;

    int i = offs[node];
    int end = i + deg[node];
    float ax = 0.0f, ay = 0.0f;

    if (FB) {
        const unsigned int* fb = (const unsigned int*)featp + lane;   // 2 bf16 per uint
        for (; i + 3 < end; i += 4) {
            int s0 = srcs[i], s1 = srcs[i + 1], s2 = srcs[i + 2], s3 = srcs[i + 3];
            float n0 = norm[s0], n1 = norm[s1], n2 = norm[s2], n3 = norm[s3];
            unsigned int u0 = fb[(size_t)s0 * 64], u1 = fb[(size_t)s1 * 64];
            unsigned int u2 = fb[(size_t)s2 * 64], u3 = fb[(size_t)s3 * 64];
            ax += __uint_as_float(u0 << 16) * n0 + __uint_as_float(u1 << 16) * n1
                + __uint_as_float(u2 << 16) * n2 + __uint_as_float(u3 << 16) * n3;
            ay += __uint_as_float(u0 & 0xffff0000u) * n0 + __uint_as_float(u1 & 0xffff0000u) * n1
                + __uint_as_float(u2 & 0xffff0000u) * n2 + __uint_as_float(u3 & 0xffff0000u) * n3;
        }
        for (; i < end; ++i) {
            int s = srcs[i];
            float n = norm[s];
            unsigned int u = fb[(size_t)s * 64];
            ax += __uint_as_float(u << 16) * n;
            ay += __uint_as_float(u & 0xffff0000u) * n;
        }
    } else {
        const float* fb = (const float*)featp + 2 * lane;
        for (; i + 3 < end; i += 4) {
            int s0 = srcs[i], s1 = srcs[i + 1], s2 = srcs[i + 2], s3 = srcs[i + 3];
            float n0 = norm[s0], n1 = norm[s1], n2 = norm[s2], n3 = norm[s3];
            float2 f0 = *(const float2*)(fb + (size_t)s0 * D);
            float2 f1 = *(const float2*)(fb + (size_t)s1 * D);
            float2 f2 = *(const float2*)(fb + (size_t)s2 * D);
            float2 f3 = *(const float2*)(fb + (size_t)s3 * D);
            ax += f0.x * n0 + f1.x * n1 + f2.x * n2 + f3.x * n3;
            ay += f0.y * n0 + f1.y * n1 + f2.y * n2 + f3.y * n3;
        }
        for (; i < end; ++i) {
            int s = srcs[i];
            float n = norm[s];
            float2 f = *(const float2*)(fb + (size_t)s * D);
            ax += f.x * n;
            ay += f.y * n;
        }
    }
    unsigned int packed = (unsigned int)f2bf(ax) | ((unsigned int)f2bf(ay) << 16);
    *(unsigned int*)(aggbf + (size_t)node * D + 2 * lane) = packed;
}

// ---- MFMA GEMM: h = (Abf @ Wbf^T + b) * norm ; BN col stats ----
// Block = 256 thr = 4 waves; block covers 64 rows; wave w covers cols [32w,32w+32).
// Per wave: B-frags [2 ct][4 kc] in registers (W row-major IS B-frag order);
// per 16-row tile: 4 A-frag global loads (16B/lane) + 8 MFMAs.
// Layouts (HW-verified): A[m=lane&15][k=(lane>>4)*8+j]; D col=lane&15, row=(lane>>4)*4+reg.
__global__ __launch_bounds__(256) void k_gemm(
        const unsigned short* __restrict__ Abf,   // nN x 128 bf16
        const unsigned short* __restrict__ Wbf,   // 128 x 128 bf16 row-major
        const float* __restrict__ b,
        const float* __restrict__ norm,
        float* __restrict__ h,                    // = d_out
        float* __restrict__ colsum, float* __restrict__ colsq,
        int nN) {
    const int tid = threadIdx.x;
    const int lane = tid & 63;
    const int wv = tid >> 6;
    const int wcol0 = wv * 32;
    const int l15 = lane & 15;
    const int lq = lane >> 4;
    const int row0 = blockIdx.x * 64;

    short8 bfrag[2][4];
    #pragma unroll
    for (int ct = 0; ct < 2; ++ct) {
        int n = wcol0 + ct * 16 + l15;
        #pragma unroll
        for (int kc = 0; kc < 4; ++kc)
            bfrag[ct][kc] = *(const short8*)(Wbf + n * 128 + kc * 32 + lq * 8);
    }
    const float bc0 = b[wcol0 + l15], bc1 = b[wcol0 + 16 + l15];

    float s1[2] = {0.0f, 0.0f}, s2[2] = {0.0f, 0.0f};

    for (int rt = 0; rt < 4; ++rt) {
        int r0 = row0 + rt * 16;
        int arow = r0 + l15;
        int arc = arow < nN ? arow : (nN - 1);     // clamp; garbage rows never stored
        short8 afrag[4];
        #pragma unroll
        for (int kc = 0; kc < 4; ++kc)
            afrag[kc] = *(const short8*)(Abf + (size_t)arc * 128 + kc * 32 + lq * 8);

        f32x4 acc0 = {0.0f, 0.0f, 0.0f, 0.0f};
        f32x4 acc1 = {0.0f, 0.0f, 0.0f, 0.0f};
        #pragma unroll
        for (int kc = 0; kc < 4; ++kc) {
            acc0 = __builtin_amdgcn_mfma_f32_16x16x32_bf16(afrag[kc], bfrag[0][kc], acc0, 0, 0, 0);
            acc1 = __builtin_amdgcn_mfma_f32_16x16x32_bf16(afrag[kc], bfrag[1][kc], acc1, 0, 0, 0);
        }

        #pragma unroll
        for (int reg = 0; reg < 4; ++reg) {
            int row = r0 + lq * 4 + reg;
            if (row < nN) {
                float nm = norm[row];
                float v0 = (acc0[reg] + bc0) * nm;
                float v1 = (acc1[reg] + bc1) * nm;
                h[(size_t)row * 128 + wcol0 + l15] = v0;
                h[(size_t)row * 128 + wcol0 + 16 + l15] = v1;
                s1[0] += v0; s2[0] += v0 * v0;
                s1[1] += v1; s2[1] += v1 * v1;
            }
        }
    }

    // reduce over the 4 lanes sharing a column (lane ^ 16, ^ 32)
    #pragma unroll
    for (int ct = 0; ct < 2; ++ct) {
        s1[ct] += __shfl_xor(s1[ct], 16, 64);
        s1[ct] += __shfl_xor(s1[ct], 32, 64);
        s2[ct] += __shfl_xor(s2[ct], 16, 64);
        s2[ct] += __shfl_xor(s2[ct], 32, 64);
    }
    if (lane < 16) {
        atomicAdd(&colsum[wcol0 + lane], s1[0]);
        atomicAdd(&colsq [wcol0 + lane], s2[0]);
        atomicAdd(&colsum[wcol0 + 16 + lane], s1[1]);
        atomicAdd(&colsq [wcol0 + 16 + lane], s2[1]);
    }
}

// ---- BN parameter fold ----
__global__ void k_bnparam(const float* __restrict__ colsum, const float* __restrict__ colsq,
                          const float* __restrict__ gamma, const float* __restrict__ beta,
                          float* __restrict__ scale, float* __restrict__ shift, int nN) {
    int j = threadIdx.x;
    float inv_n = 1.0f / (float)nN;
    float mean = colsum[j] * inv_n;
    float var = colsq[j] * inv_n - mean * mean;
    float sc = gamma[j] * rsqrtf(var + BN_EPS);
    scale[j] = sc;
    shift[j] = beta[j] - mean * sc;
}

// ---- out = feat + relu(h*scale + shift), in-place over h (= d_out) ----
__global__ void k_out(float* __restrict__ h, const float* __restrict__ feat,
                      const float* __restrict__ scale, const float* __restrict__ shift,
                      int total4) {
    int t = blockIdx.x * 256 + threadIdx.x;
    if (t >= total4) return;
    int base = t * 4;
    int j = base & 127;
    float4 hv = *(const float4*)(h + base);
    float4 fv = *(const float4*)(feat + base);
    float4 o;
    o.x = fv.x + fmaxf(hv.x * scale[j + 0] + shift[j + 0], 0.0f);
    o.y = fv.y + fmaxf(hv.y * scale[j + 1] + shift[j + 1], 0.0f);
    o.z = fv.z + fmaxf(hv.z * scale[j + 2] + shift[j + 2], 0.0f);
    o.w = fv.w + fmaxf(hv.w * scale[j + 3] + shift[j + 3], 0.0f);
    *(float4*)(h + base) = o;
}

extern "C" void kernel_launch(void* const* d_in, const int* in_sizes, int n_in,
                              void* d_out, int out_size, void* d_ws, size_t ws_size,
                              hipStream_t stream) {
    const float* feat  = (const float*)d_in[0];
    const float* W     = (const float*)d_in[1];
    const float* b     = (const float*)d_in[2];
    const float* gamma = (const float*)d_in[3];
    const float* beta  = (const float*)d_in[4];
    const int* esrc = (const int*)d_in[5];
    const int* edst = (const int*)d_in[6];

    const int nN = in_sizes[0] / D;
    const int nE = in_sizes[5];

    float* h = (float*)d_out;

    // workspace layout: 16B-aligned big arrays first
    unsigned short* Wbf   = (unsigned short*)d_ws;            // 128*128
    unsigned short* aggbf = Wbf + 128 * 128;                  // nN*128
    int*   deg     = (int*)(aggbf + (size_t)nN * D);          // nN
    int*   offs    = deg + nN;                                // nN
    int*   cursor  = offs + nN;                               // nN
    int*   srcs    = cursor + nN;                             // nE
    float* norm    = (float*)(srcs + nE);                     // nN
    float* colsum  = norm + nN;                               // 128
    float* colsq   = colsum + 128;                            // 128
    float* scale   = colsq + 128;                             // 128
    float* shift   = scale + 128;                             // 128
    int*   counter = (int*)(shift + 128);                     // 1
    unsigned short* featbf = (unsigned short*)(counter + 1);  // nN*128 (optional)

    size_t need_full = (size_t)((char*)(featbf + (size_t)nN * D) - (char*)d_ws);
    bool useFB = ws_size >= need_full;

    hipMemsetAsync(deg, 0, (size_t)nN * sizeof(int), stream);
    hipMemsetAsync(colsum, 0, (4 * 128 + 1) * sizeof(float), stream);

    // casts
    k_cast<<<(128 * 128 / 4 + 255) / 256, 256, 0, stream>>>((const float4*)W, (ushort4*)Wbf, 128 * 128 / 4);
    if (useFB) {
        int n4 = nN * D / 4;
        k_cast<<<(n4 + 255) / 256, 256, 0, stream>>>((const float4*)feat, (ushort4*)featbf, n4);
    }

    k_hist<<<(nE + 255) / 256, 256, 0, stream>>>(edst, deg, nE);
    k_claim<<<(nN + 255) / 256, 256, 0, stream>>>(deg, offs, cursor, norm, counter, nN);
    k_bucket<<<(nE + 255) / 256, 256, 0, stream>>>(esrc, edst, cursor, srcs, nE);

    int gblocks = (nN * 64 + 255) / 256;
    if (useFB)
        k_gather<true><<<gblocks, 256, 0, stream>>>(offs, deg, srcs, featbf, norm, aggbf, nN);
    else
        k_gather<false><<<gblocks, 256, 0, stream>>>(offs, deg, srcs, feat, norm, aggbf, nN);

    k_gemm<<<(nN + 63) / 64, 256, 0, stream>>>(aggbf, Wbf, b, norm, h, colsum, colsq, nN);
    k_bnparam<<<1, 128, 0, stream>>>(colsum, colsq, gamma, beta, scale, shift, nN);

    int total4 = nN * D / 4;
    k_out<<<(total4 + 255) / 256, 256, 0, stream>>>(h, feat, scale, shift, total4);
}